// Round 19
// baseline (61.792 us; speedup 1.0000x reference)
//
#include <hip/hip_runtime.h>
#include <stdint.h>

#define NB 128        // batch rows
#define NV 128000     // vocab
#define TOPC 63       // max rank ever sampleable (top_ks <= 63)

// ---- fast path geometry ----
#define JPB 25                // chunks per row
#define CH 5120               // floats per chunk (NV/JPB)
#define CH4 1280              // float4s per chunk
#define K1T 256               // threads per block (all kernels)
#define QPT 5                 // float4s per thread (CH4/K1T)
#define HB 8192               // fallback histogram bins (sortkey >> 19)
#define HBW (HB / 2)          // u16x2 words, parity-packed
#define WINSD 2.2f            // window width in sigma_s below chunk max
#define CSLOT 104             // candidate slots per chunk
#define SCCAP (JPB * CSLOT)   // 2600 max candidates per row
#define NHB 2048              // narrow-hist bins (p_bits >> 21)
#define SNCAP 256             // survivor capacity (sorted set)
#define NBLK1 (NB * JPB)      // 3200 blocks for k0/k1

// ws layout (bytes) -- total 2,035,712 (proven available)
#define WS_CS_OFF   0                                   // u32 [NBLK1][CSLOT]
#define WS_CS_BYTES ((size_t)NBLK1 * CSLOT * 4)
#define WS_M_OFF    (WS_CS_BYTES)                       // f32 [NBLK1]
#define WS_S_OFF    (WS_M_OFF + NBLK1 * 4)
#define WS_CNT_OFF  (WS_S_OFF + NBLK1 * 4)
#define WS_CTR_OFF  (WS_CNT_OFF + NBLK1 * 4)            // (unused)
#define WS_CI_OFF   (WS_CTR_OFF + NB * 4)               // u16 [NBLK1][CSLOT]
#define WS_NEED     (WS_CI_OFF + (size_t)NBLK1 * CSLOT * 2)

// ---- fallback (round-2 monolithic) geometry ----
#define NT 1024
#define NV4 (NV / 4)
#define NBINS 16384
#define CCAP 2048

typedef float f4 __attribute__((ext_vector_type(4)));

__device__ __forceinline__ uint32_t rotl32(uint32_t v, uint32_t d) {
  return (v << d) | (v >> (32u - d));
}

// Threefry-2x32, 20 rounds, matching jax._src.prng.threefry2x32.
__device__ __forceinline__ void threefry2x32(uint32_t k0, uint32_t k1,
                                             uint32_t x0, uint32_t x1,
                                             uint32_t& o0, uint32_t& o1) {
  uint32_t ks2 = k0 ^ k1 ^ 0x1BD11BDAu;
  x0 += k0; x1 += k1;
#define TF_ROUND(r) { x0 += x1; x1 = rotl32(x1, (r)); x1 ^= x0; }
  TF_ROUND(13) TF_ROUND(15) TF_ROUND(26) TF_ROUND(6)
  x0 += k1;  x1 += ks2 + 1u;
  TF_ROUND(17) TF_ROUND(29) TF_ROUND(16) TF_ROUND(24)
  x0 += ks2; x1 += k0 + 2u;
  TF_ROUND(13) TF_ROUND(15) TF_ROUND(26) TF_ROUND(6)
  x0 += k0;  x1 += k1 + 3u;
  TF_ROUND(17) TF_ROUND(29) TF_ROUND(16) TF_ROUND(24)
  x0 += k1;  x1 += ks2 + 4u;
  TF_ROUND(13) TF_ROUND(15) TF_ROUND(26) TF_ROUND(6)
  x0 += ks2; x1 += k0 + 5u;
#undef TF_ROUND
  o0 = x0; o1 = x1;
}

// partitionable random_bits, u32 = xor of the two threefry words (verified round 2)
__device__ __forceinline__ uint32_t jax_random_bits_u32(uint64_t n) {
  uint32_t o0, o1;
  threefry2x32(0u, 42u, (uint32_t)(n >> 32), (uint32_t)n, o0, o1);
  return o0 ^ o1;
}

// JAX: uniform(key, minval=tiny, maxval=1.) -> gumbel = -log(-log(u))
__device__ __forceinline__ float gumbel_from_bits(uint32_t bits) {
  const float tiny = 1.17549435e-38f;
  float f = __uint_as_float(0x3f800000u | (bits >> 9)) - 1.0f;  // [0,1)
  float u = f * 1.0f + tiny;
  u = fmaxf(tiny, u);
  return -logf(-logf(u));
}

// Monotone (ascending) uint mapping of float ordering.
__device__ __forceinline__ uint32_t sortkey(float x) {
  uint32_t b = __float_as_uint(x);
  uint32_t mask = (uint32_t)((int32_t)b >> 31) | 0x80000000u;
  return b ^ mask;
}

// Markstein exact division by block-invariant st: bit-identical to a/st
// (verified rounds 11-16: passed with absmax at bf16 rounding floor).
__device__ __forceinline__ float div_exact(float a, float st, float ry) {
  float q0 = a * ry;
  float r  = __builtin_fmaf(-st, q0, a);
  return __builtin_fmaf(r, ry, q0);
}

// ======================= k0: pure scale+store stream =======================
// Structurally a float4 copy with a fused multiply-chain -- the m13 pattern
// that hits 6.3 TB/s. Normal stores keep `scaled` L3-resident for k1_select.
__global__ __launch_bounds__(K1T) void k0_stream(
    const float* __restrict__ logits, const float* __restrict__ temps,
    float* __restrict__ out) {
  const int bid = blockIdx.x;
  const int r = bid / JPB, j = bid - r * JPB;
  const int t = threadIdx.x;
  const float temp = temps[r];
  const float st = (temp == 0.0f) ? 1.0f : temp;
  const float ry = 1.0f / st;
  const f4* __restrict__ lrow4 = (const f4*)(logits + (size_t)r * NV + (size_t)j * CH);
  f4* __restrict__ srow4 = (f4*)(out + NB + (size_t)r * NV + (size_t)j * CH);
  #pragma unroll
  for (int q = 0; q < QPT; ++q) {
    int i = q * K1T + t;
    f4 x = lrow4[i];
    f4 s;
    s.x = div_exact(x.x, st, ry);
    s.y = div_exact(x.y, st, ry);
    s.z = div_exact(x.z, st, ry);
    s.w = div_exact(x.w, st, ry);
    srow4[i] = s;
  }
}

// ======================= k1: per-chunk select (reads scaled, L3-hot) ========
// Byte-identical selection logic to r16's k1; source of s values is the
// just-written scaled buffer (bit-identical floats -> identical ids).
__global__ __launch_bounds__(K1T) void k1_select(
    const float* __restrict__ out_scaled, const float* __restrict__ temps,
    uint32_t* __restrict__ cand_s, uint16_t* __restrict__ cand_i,
    float* __restrict__ m_arr, float* __restrict__ S_arr,
    uint32_t* __restrict__ cnt_arr) {

  __shared__ uint32_t histw[HBW];         // [0..255] = small hist; full = fallback
  __shared__ uint32_t ssum[K1T];          // fallback scan
  __shared__ float swm[4], sws[4];
  __shared__ uint32_t wtot[4];
  __shared__ int s_tstar;
  __shared__ uint32_t s_cutbin, s_cutkey, s_lcnt;

  const int bid = blockIdx.x;
  const int r = bid / JPB, j = bid - r * JPB;
  const int t = threadIdx.x;
  const int lane = t & 63, wv = t >> 6;
  const float temp = temps[r];
  const float st = (temp == 0.0f) ? 1.0f : temp;
  const float ry = 1.0f / st;

  const f4* __restrict__ srow4 =
      (const f4*)(out_scaled + NB + (size_t)r * NV + (size_t)j * CH);

  histw[t] = 0u;                          // zero the 256 small bins (K1T==256)
  if (t == 0) { s_lcnt = 0u; s_tstar = K1T - 1; s_cutbin = 255u; }

  // ---- load scaled values (L3-hot) + 4-chain sum/max ----
  f4 sreg[QPT];
  #pragma unroll
  for (int q = 0; q < QPT; ++q)
    sreg[q] = srow4[q * K1T + t];

  float mx0 = -INFINITY, mx1 = -INFINITY, mx2 = -INFINITY, mx3 = -INFINITY;
  float sm0 = 0.0f, sm1 = 0.0f, sm2 = 0.0f, sm3 = 0.0f;
  #pragma unroll
  for (int q = 0; q < QPT; ++q) {
    f4 s = sreg[q];
    mx0 = fmaxf(mx0, s.x); mx1 = fmaxf(mx1, s.y);
    mx2 = fmaxf(mx2, s.z); mx3 = fmaxf(mx3, s.w);
    sm0 += __expf(s.x); sm1 += __expf(s.y);
    sm2 += __expf(s.z); sm3 += __expf(s.w);
  }
  float mx = fmaxf(fmaxf(mx0, mx1), fmaxf(mx2, mx3));
  float sum = (sm0 + sm1) + (sm2 + sm3);
  #pragma unroll
  for (int off = 32; off > 0; off >>= 1) {
    mx = fmaxf(mx, __shfl_xor(mx, off));
    sum += __shfl_xor(sum, off);
  }
  if (lane == 0) { swm[wv] = mx; sws[wv] = sum; }
  __syncthreads();                        // also publishes zeroed small hist
  const float mxb = fmaxf(fmaxf(swm[0], swm[1]), fmaxf(swm[2], swm[3]));
  if (t == 0) {
    m_arr[bid] = mxb;
    S_arr[bid] = sws[0] + sws[1] + sws[2] + sws[3];
  }
  const float F = (256.0f / WINSD) * st;

  // ---- pass B: windowed 256-bin hist (bin 0 = chunk max) ----
  #pragma unroll
  for (int q = 0; q < QPT; ++q) {
    float sv[4] = {sreg[q].x, sreg[q].y, sreg[q].z, sreg[q].w};
    #pragma unroll
    for (int c = 0; c < 4; ++c) {
      float d = (mxb - sv[c]) * F;        // >= 0
      if (d < 256.0f) atomicAdd(&histw[(uint32_t)d], 1u);
    }
  }
  __syncthreads();

  // ---- prefix over 256 bins; winner bin where prefix first reaches 63 ----
  {
    uint32_t c = histw[t];
    uint32_t ps = c;
    #pragma unroll
    for (int off = 1; off < 64; off <<= 1) {
      uint32_t v = __shfl_up(ps, off);
      if (lane >= off) ps += v;
    }
    if (lane == 63) wtot[wv] = ps;
    __syncthreads();
    uint32_t add = 0;
    #pragma unroll
    for (int w2 = 0; w2 < 4; ++w2)
      if (w2 < wv) add += wtot[w2];
    ps += add;                             // inclusive prefix over bins 0..t
    if (ps >= 63u && (ps - c) < 63u) s_cutbin = (uint32_t)t;
  }
  __syncthreads();
  const uint32_t cutbin = s_cutbin;

  // ---- pass C: extract bin <= cutbin (IDENTICAL float expr as counting) ----
  uint32_t* __restrict__ mys = cand_s + (size_t)bid * CSLOT;
  uint16_t* __restrict__ myi = cand_i + (size_t)bid * CSLOT;
  #pragma unroll
  for (int q = 0; q < QPT; ++q) {
    float sv[4] = {sreg[q].x, sreg[q].y, sreg[q].z, sreg[q].w};
    #pragma unroll
    for (int c = 0; c < 4; ++c) {
      float d = (mxb - sv[c]) * F;
      if (d < 256.0f && (uint32_t)d <= cutbin) {
        uint32_t pos = atomicAdd(&s_lcnt, 1u);
        if (pos < CSLOT) {
          mys[pos] = __float_as_uint(sv[c]);
          myi[pos] = (uint16_t)((q * K1T + t) * 4 + c);
        }
      }
    }
  }
  __syncthreads();
  const uint32_t lc = s_lcnt;
  if (lc >= 63u && lc <= (uint32_t)CSLOT) {
    if (t == 0) cnt_arr[bid] = lc;
    return;                                // common path done
  }

  // ========== exact fallback: full 8192-bin hist (r13-proven code) ==========
  if (t == 0) s_lcnt = 0u;
  for (int i = t; i < HBW; i += K1T) histw[i] = 0u;
  __syncthreads();
  #pragma unroll
  for (int q = 0; q < QPT; ++q) {
    float sv[4] = {sreg[q].x, sreg[q].y, sreg[q].z, sreg[q].w};
    #pragma unroll
    for (int c = 0; c < 4; ++c) {
      uint32_t b = sortkey(sv[c]) >> 19;
      atomicAdd(&histw[b >> 1], (b & 1) ? 65536u : 1u);
    }
  }
  __syncthreads();
  uint32_t sloc = 0;
  #pragma unroll
  for (int u = 0; u < 16; ++u) {
    uint32_t w = histw[t * 16 + u];
    sloc += (w & 0xFFFFu) + (w >> 16);
  }
  ssum[t] = sloc;
  __syncthreads();
  for (int off = 1; off < K1T; off <<= 1) {
    uint32_t v = ssum[t] + ((t + off < K1T) ? ssum[t + off] : 0u);
    __syncthreads();
    ssum[t] = v;
    __syncthreads();
  }
  if (ssum[t] >= 63u && (t == K1T - 1 || ssum[t + 1] < 63u)) s_tstar = t;
  __syncthreads();
  if (t == 0) {
    int ts = s_tstar;
    uint32_t running = (ts == K1T - 1) ? 0u : ssum[ts + 1];
    int cb = ts * 32;
    for (int q = 31; q >= 0; --q) {
      uint32_t w = histw[ts * 16 + (q >> 1)];
      uint32_t c = (q & 1) ? (w >> 16) : (w & 0xFFFFu);
      running += c;
      if (running >= 63u) { cb = ts * 32 + q; break; }
    }
    s_cutkey = (uint32_t)cb << 19;
  }
  __syncthreads();
  const uint32_t cutkey = s_cutkey;
  #pragma unroll
  for (int q = 0; q < QPT; ++q) {
    float sv[4] = {sreg[q].x, sreg[q].y, sreg[q].z, sreg[q].w};
    #pragma unroll
    for (int c = 0; c < 4; ++c) {
      if (sortkey(sv[c]) >= cutkey) {
        uint32_t pos = atomicAdd(&s_lcnt, 1u);
        if (pos < CSLOT) {
          mys[pos] = __float_as_uint(sv[c]);
          myi[pos] = (uint16_t)((q * K1T + t) * 4 + c);
        }
      }
    }
  }
  __syncthreads();
  if (t == 0) cnt_arr[bid] = (s_lcnt < CSLOT) ? s_lcnt : (uint32_t)CSLOT;
}

// ======================= k2: per-row finalize (r14-16, passed) ==============
__global__ __launch_bounds__(K1T) void k2_final(
    const float* __restrict__ temps, const float* __restrict__ topps,
    const float* __restrict__ topks, const uint32_t* __restrict__ cand_s,
    const uint16_t* __restrict__ cand_i, const float* __restrict__ m_arr,
    const float* __restrict__ S_arr, const uint32_t* __restrict__ cnt_arr,
    float* __restrict__ out) {

  __shared__ unsigned long long sc[SCCAP];   // 20.8 KB (holey staging)
  __shared__ uint32_t nhist[NHB];            // 8 KB
  __shared__ unsigned long long sn[SNCAP];   // 2 KB
  __shared__ float sm8[32], ss8[32];
  __shared__ uint32_t scnt8[JPB];
  __shared__ uint32_t swsum[4];
  __shared__ uint32_t s_cutp, s_scnt;
  __shared__ float s_m, s_Z;
  __shared__ float sp[TOPC], scum[TOPC], slv[TOPC];
  __shared__ int sidx_[TOPC];

  const int r = blockIdx.x;
  const int t = threadIdx.x;
  const int lane = t & 63, wv = t >> 6;
  const float temp = temps[r];

  if (t < 32) {
    sm8[t] = (t < JPB) ? m_arr[r * JPB + t] : -INFINITY;
    ss8[t] = (t < JPB) ? S_arr[r * JPB + t] : 0.0f;
  }
  if (t < JPB) scnt8[t] = cnt_arr[r * JPB + t];
  for (int i = t; i < NHB; i += K1T) nhist[i] = 0u;
  __syncthreads();
  if (t == 0) {
    float m = -INFINITY;
    for (int q = 0; q < JPB; ++q) m = fmaxf(m, sm8[q]);
    float Sr = 0.0f;
    for (int q = 0; q < JPB; ++q) Sr += ss8[q];
    s_m = m;
    s_Z = Sr * expf(-m);   // uniform per-row scalar (order-safe)
    s_scnt = 0u;
  }
  __syncthreads();
  const float m = s_m, Z = s_Z;

  // gather: direct (chunk, slot) indexing -- no linear search, holes skipped
  for (int e = t; e < SCCAP; e += K1T) {
    int q = e / CSLOT;
    int slot = e - q * CSLOT;
    if (slot < (int)scnt8[q]) {
      int gs = (r * JPB + q) * CSLOT + slot;
      float s = __uint_as_float(cand_s[gs]);
      uint32_t idx = (uint32_t)q * CH + (uint32_t)cand_i[gs];
      float p = expf(s - m) / Z;
      sc[e] = ((unsigned long long)__float_as_uint(p) << 32)
            | (unsigned long long)(0xFFFFFFFFu - idx);
      atomicAdd(&nhist[__float_as_uint(p) >> 21], 1u);
    }
  }
  __syncthreads();

  // narrow cut on p-bits: thread t owns bins [t*8, t*8+8)
  uint32_t nloc = 0;
  #pragma unroll
  for (int u = 0; u < 8; ++u) nloc += nhist[t * 8 + u];
  uint32_t ns = nloc;
  #pragma unroll
  for (int off = 1; off < 64; off <<= 1) {
    uint32_t v = __shfl_down(ns, off);
    if (lane + off < 64) ns += v;
  }
  if (lane == 0) swsum[wv] = ns;
  __syncthreads();
  #pragma unroll
  for (int w2 = 0; w2 < 4; ++w2)
    if (w2 > wv) ns += swsum[w2];
  if (ns >= 63u && (ns - nloc) < 63u) {
    uint32_t running = ns - nloc;
    int cutbin = t * 8;
    for (int u = 7; u >= 0; --u) {
      running += nhist[t * 8 + u];
      if (running >= 63u) { cutbin = t * 8 + u; break; }
    }
    s_cutp = (uint32_t)cutbin << 21;
  }
  __syncthreads();
  const uint32_t cutp = s_cutp;

  for (int e = t; e < SCCAP; e += K1T) {
    int q = e / CSLOT;
    int slot = e - q * CSLOT;
    if (slot < (int)scnt8[q]) {
      unsigned long long v = sc[e];
      if ((uint32_t)(v >> 32) >= cutp) {
        uint32_t pos = atomicAdd(&s_scnt, 1u);
        if (pos < SNCAP) sn[pos] = v;
      }
    }
  }
  __syncthreads();
  const uint32_t scnt = s_scnt;
  if (t < SNCAP && t >= (int)scnt) sn[t] = 0ull;
  __syncthreads();

  // bitonic sort SNCAP keys descending => (p desc, idx asc)
  for (int k = 2; k <= SNCAP; k <<= 1) {
    for (int jj = k >> 1; jj > 0; jj >>= 1) {
      int e = t;
      int ixj = e ^ jj;
      if (ixj > e) {
        unsigned long long a = sn[e], c = sn[ixj];
        bool desc = ((e & k) == 0);
        if (desc ? (a < c) : (a > c)) { sn[e] = c; sn[ixj] = a; }
      }
      __syncthreads();
    }
  }

  // ---- top-63 tail (validated rounds 2-16) ----
  if (t < TOPC) {
    unsigned long long kv = sn[t];
    sp[t] = __uint_as_float((uint32_t)(kv >> 32));
    sidx_[t] = (int)(0xFFFFFFFFu - (uint32_t)(kv & 0xFFFFFFFFull));
  }
  __syncthreads();
  if (t == 0) {
    float L0[63], L1[31], L2[15], L3[7], L4[3];
    for (int i = 0; i < 63; ++i) L0[i] = sp[i];
    for (int i = 0; i < 31; ++i) L1[i] = L0[2*i] + L0[2*i+1];
    for (int i = 0; i < 15; ++i) L2[i] = L1[2*i] + L1[2*i+1];
    for (int i = 0; i < 7;  ++i) L3[i] = L2[2*i] + L2[2*i+1];
    for (int i = 0; i < 3;  ++i) L4[i] = L3[2*i] + L3[2*i+1];
    float S5 = L4[0] + L4[1];
    float S4[3]; S4[0] = L4[0]; S4[1] = S5; S4[2] = S5 + L4[2];
    float S3[7]; S3[0] = L3[0];
    for (int k = 0; k < 3; ++k) { S3[2*k+1] = S4[k]; if (2*k+2 < 7)  S3[2*k+2] = S4[k] + L3[2*k+2]; }
    float S2[15]; S2[0] = L2[0];
    for (int k = 0; k < 7; ++k) { S2[2*k+1] = S3[k]; if (2*k+2 < 15) S2[2*k+2] = S3[k] + L2[2*k+2]; }
    float S1[31]; S1[0] = L1[0];
    for (int k = 0; k < 15; ++k){ S1[2*k+1] = S2[k]; if (2*k+2 < 31) S1[2*k+2] = S2[k] + L1[2*k+2]; }
    scum[0] = L0[0];
    for (int k = 0; k < 31; ++k){ scum[2*k+1] = S1[k]; if (2*k+2 < 63) scum[2*k+2] = S1[k] + L0[2*k+2]; }
  }
  __syncthreads();
  if (t < TOPC) {
    const float topp = topps[r];
    const float topk = topks[r];
    bool keep = (((float)t < topk) && ((scum[t] - sp[t]) < topp)) || (t == 0);
    uint32_t bits = jax_random_bits_u32((uint64_t)r * NV + (uint64_t)t);
    float g = gumbel_from_bits(bits);
    slv[t] = keep ? (logf(sp[t]) + g) : -INFINITY;
  }
  __syncthreads();
  if (t == 0) {
    float best = slv[0]; int br = 0;
    for (int q = 1; q < TOPC; ++q)
      if (slv[q] > best) { best = slv[q]; br = q; }
    int id = (temp == 0.0f) ? sidx_[0] : sidx_[br];
    out[r] = (float)id;
  }
}

// ======================= fallback: round-2 monolithic kernel =======================

__global__ __launch_bounds__(NT) void sampler_kernel(
    const float* __restrict__ logits, const float* __restrict__ temps,
    const float* __restrict__ topps, const float* __restrict__ topks,
    float* __restrict__ out) {

  __shared__ union {
    uint32_t hist[NBINS];
    unsigned long long cand[CCAP];
  } sh;
  __shared__ uint32_t ssum[NT];
  __shared__ float redf[NT];
  __shared__ uint32_t s_cutkey, s_cnt;
  __shared__ int s_tstar;
  __shared__ float sp[TOPC], scum[TOPC], slv[TOPC];
  __shared__ int sidx_[TOPC];

  const int b = blockIdx.x;
  const int t = threadIdx.x;
  const float temp = temps[b];
  const float st = (temp == 0.0f) ? 1.0f : temp;
  const float topp = topps[b];
  const float topk = topks[b];

  const float4* __restrict__ lrow = (const float4*)(logits + (size_t)b * NV);
  float4* __restrict__ srow = (float4*)(out + NB + (size_t)b * NV);

  for (int i = t; i < NBINS; i += NT) sh.hist[i] = 0u;
  if (t == 0) s_tstar = NT - 1;

  float lmax = -INFINITY;
  for (int i = t; i < NV4; i += NT) {
    float4 x = lrow[i];
    float4 s;
    s.x = x.x / st; s.y = x.y / st; s.z = x.z / st; s.w = x.w / st;
    srow[i] = s;
    lmax = fmaxf(lmax, fmaxf(fmaxf(s.x, s.y), fmaxf(s.z, s.w)));
  }
  redf[t] = lmax;
  __syncthreads();
  for (int off = NT / 2; off > 0; off >>= 1) {
    if (t < off) redf[t] = fmaxf(redf[t], redf[t + off]);
    __syncthreads();
  }
  const float m = redf[0];
  __syncthreads();

  float lsum = 0.0f;
  for (int i = t; i < NV4; i += NT) {
    float4 x = lrow[i];
    float s0 = x.x / st, s1 = x.y / st, s2 = x.z / st, s3 = x.w / st;
    lsum += expf(s0 - m); lsum += expf(s1 - m);
    lsum += expf(s2 - m); lsum += expf(s3 - m);
    atomicAdd(&sh.hist[sortkey(s0) >> 18], 1u);
    atomicAdd(&sh.hist[sortkey(s1) >> 18], 1u);
    atomicAdd(&sh.hist[sortkey(s2) >> 18], 1u);
    atomicAdd(&sh.hist[sortkey(s3) >> 18], 1u);
  }
  redf[t] = lsum;
  __syncthreads();
  for (int off = NT / 2; off > 0; off >>= 1) {
    if (t < off) redf[t] += redf[t + off];
    __syncthreads();
  }
  const float Z = redf[0];
  __syncthreads();

  uint32_t sloc = 0;
  #pragma unroll
  for (int j = 0; j < 16; ++j) sloc += sh.hist[t * 16 + j];
  ssum[t] = sloc;
  __syncthreads();
  for (int off = 1; off < NT; off <<= 1) {
    uint32_t v = ssum[t] + ((t + off < NT) ? ssum[t + off] : 0u);
    __syncthreads();
    ssum[t] = v;
    __syncthreads();
  }
  if (ssum[t] >= 63u && (t == NT - 1 || ssum[t + 1] < 63u)) s_tstar = t;
  __syncthreads();
  if (t == 0) {
    int ts = s_tstar;
    uint32_t running = (ts == NT - 1) ? 0u : ssum[ts + 1];
    int cutbin = ts * 16;
    for (int j = 15; j >= 0; --j) {
      running += sh.hist[ts * 16 + j];
      if (running >= 63u) { cutbin = ts * 16 + j; break; }
    }
    s_cutkey = (uint32_t)cutbin << 18;
    s_cnt = 0u;
  }
  __syncthreads();
  const uint32_t cutkey = s_cutkey;

  for (int i = t; i < NV4; i += NT) {
    float4 x = lrow[i];
    float sv[4];
    sv[0] = x.x / st; sv[1] = x.y / st; sv[2] = x.z / st; sv[3] = x.w / st;
    #pragma unroll
    for (int j = 0; j < 4; ++j) {
      uint32_t key = sortkey(sv[j]);
      if (key >= cutkey) {
        float p = expf(sv[j] - m) / Z;
        uint32_t pos = atomicAdd(&s_cnt, 1u);
        if (pos < CCAP) {
          uint32_t idx = (uint32_t)(i * 4 + j);
          sh.cand[pos] = ((unsigned long long)__float_as_uint(p) << 32)
                       | (unsigned long long)(0xFFFFFFFFu - idx);
        }
      }
    }
  }
  __syncthreads();
  const uint32_t cnt = s_cnt;
  for (int e = t; e < CCAP; e += NT)
    if ((uint32_t)e >= cnt) sh.cand[e] = 0ull;
  __syncthreads();

  for (uint32_t k = 2; k <= CCAP; k <<= 1) {
    for (uint32_t j = k >> 1; j > 0; j >>= 1) {
      for (int e = t; e < CCAP; e += NT) {
        uint32_t ixj = (uint32_t)e ^ j;
        if (ixj > (uint32_t)e) {
          unsigned long long a = sh.cand[e], c = sh.cand[ixj];
          bool desc = (((uint32_t)e & k) == 0u);
          if (desc ? (a < c) : (a > c)) { sh.cand[e] = c; sh.cand[ixj] = a; }
        }
      }
      __syncthreads();
    }
  }

  if (t < TOPC) {
    unsigned long long kv = sh.cand[t];
    sp[t] = __uint_as_float((uint32_t)(kv >> 32));
    sidx_[t] = (int)(0xFFFFFFFFu - (uint32_t)(kv & 0xFFFFFFFFull));
  }
  __syncthreads();
  if (t == 0) {
    float L0[63], L1[31], L2[15], L3[7], L4[3];
    for (int i = 0; i < 63; ++i) L0[i] = sp[i];
    for (int i = 0; i < 31; ++i) L1[i] = L0[2*i] + L0[2*i+1];
    for (int i = 0; i < 15; ++i) L2[i] = L1[2*i] + L1[2*i+1];
    for (int i = 0; i < 7;  ++i) L3[i] = L2[2*i] + L2[2*i+1];
    for (int i = 0; i < 3;  ++i) L4[i] = L3[2*i] + L3[2*i+1];
    float S5 = L4[0] + L4[1];
    float S4[3]; S4[0] = L4[0]; S4[1] = S5; S4[2] = S5 + L4[2];
    float S3[7]; S3[0] = L3[0];
    for (int k = 0; k < 3; ++k) { S3[2*k+1] = S4[k]; if (2*k+2 < 7)  S3[2*k+2] = S4[k] + L3[2*k+2]; }
    float S2[15]; S2[0] = L2[0];
    for (int k = 0; k < 7; ++k) { S2[2*k+1] = S3[k]; if (2*k+2 < 15) S2[2*k+2] = S3[k] + L2[2*k+2]; }
    float S1[31]; S1[0] = L1[0];
    for (int k = 0; k < 15; ++k){ S1[2*k+1] = S2[k]; if (2*k+2 < 31) S1[2*k+2] = S2[k] + L1[2*k+2]; }
    scum[0] = L0[0];
    for (int k = 0; k < 31; ++k){ scum[2*k+1] = S1[k]; if (2*k+2 < 63) scum[2*k+2] = S1[k] + L0[2*k+2]; }
  }
  __syncthreads();
  if (t < TOPC) {
    bool keep = (((float)t < topk) && ((scum[t] - sp[t]) < topp)) || (t == 0);
    uint32_t bits = jax_random_bits_u32((uint64_t)b * NV + (uint64_t)t);
    float g = gumbel_from_bits(bits);
    slv[t] = keep ? (logf(sp[t]) + g) : -INFINITY;
  }
  __syncthreads();
  if (t == 0) {
    float best = slv[0]; int br = 0;
    for (int q = 1; q < TOPC; ++q)
      if (slv[q] > best) { best = slv[q]; br = q; }
    int id = (temp == 0.0f) ? sidx_[0] : sidx_[br];
    out[b] = (float)id;
  }
}

extern "C" void kernel_launch(void* const* d_in, const int* in_sizes, int n_in,
                              void* d_out, int out_size, void* d_ws, size_t ws_size,
                              hipStream_t stream) {
  const float* logits = (const float*)d_in[0];
  const float* temps  = (const float*)d_in[1];
  const float* topps  = (const float*)d_in[2];
  const float* topks  = (const float*)d_in[3];
  float* out = (float*)d_out;

  if (ws_size >= WS_NEED) {
    uint32_t* cand_s  = (uint32_t*)((char*)d_ws + WS_CS_OFF);
    uint16_t* cand_i  = (uint16_t*)((char*)d_ws + WS_CI_OFF);
    float*    m_arr   = (float*)((char*)d_ws + WS_M_OFF);
    float*    S_arr   = (float*)((char*)d_ws + WS_S_OFF);
    uint32_t* cnt_arr = (uint32_t*)((char*)d_ws + WS_CNT_OFF);
    hipLaunchKernelGGL(k0_stream, dim3(NBLK1), dim3(K1T), 0, stream,
                       logits, temps, out);
    hipLaunchKernelGGL(k1_select, dim3(NBLK1), dim3(K1T), 0, stream,
                       out, temps, cand_s, cand_i, m_arr, S_arr, cnt_arr);
    hipLaunchKernelGGL(k2_final, dim3(NB), dim3(K1T), 0, stream,
                       temps, topps, topks, cand_s, cand_i,
                       m_arr, S_arr, cnt_arr, out);
  } else {
    hipLaunchKernelGGL(sampler_kernel, dim3(NB), dim3(NT), 0, stream,
                       logits, temps, topps, topks, out);
  }
}

// Round 20
// 48.891 us; speedup vs baseline: 1.2639x; 1.2639x over previous
//
#include <hip/hip_runtime.h>
#include <stdint.h>

#define NB 128        // batch rows
#define NV 128000     // vocab
#define TOPC 63       // max rank ever sampleable (top_ks <= 63)

// ---- fast path geometry (register-resident chunks) ----
#define JPB 25                // chunks per row
#define CH 5120               // floats per chunk (NV/JPB)
#define CH4 1280              // float4s per chunk
#define K1T 256               // threads per block (both kernels)
#define QPT 5                 // float4s per thread (CH4/K1T)
#define HB 8192               // fallback histogram bins (sortkey >> 19)
#define HBW (HB / 2)          // u16x2 words, parity-packed
#define WINSD 2.2f            // window width in sigma_s below chunk max
#define CSLOT 104             // candidate slots per chunk
#define SCCAP (JPB * CSLOT)   // 2600 max candidates per row
#define NHB 2048              // narrow-hist bins (p_bits >> 21)
#define SNCAP 256             // survivor capacity (sorted set)
#define NBLK1 (NB * JPB)      // 3200 k1 blocks

// ws layout (bytes) -- total 2,035,712 (proven available)
#define WS_CS_OFF   0                                   // u32 [NBLK1][CSLOT]
#define WS_CS_BYTES ((size_t)NBLK1 * CSLOT * 4)
#define WS_M_OFF    (WS_CS_BYTES)                       // f32 [NBLK1]
#define WS_S_OFF    (WS_M_OFF + NBLK1 * 4)
#define WS_CNT_OFF  (WS_S_OFF + NBLK1 * 4)
#define WS_CTR_OFF  (WS_CNT_OFF + NBLK1 * 4)            // (unused)
#define WS_CI_OFF   (WS_CTR_OFF + NB * 4)               // u16 [NBLK1][CSLOT]
#define WS_NEED     (WS_CI_OFF + (size_t)NBLK1 * CSLOT * 2)

// ---- fallback (round-2 monolithic) geometry ----
#define NT 1024
#define NV4 (NV / 4)
#define NBINS 16384
#define CCAP 2048

typedef float f4 __attribute__((ext_vector_type(4)));

__device__ __forceinline__ uint32_t rotl32(uint32_t v, uint32_t d) {
  return (v << d) | (v >> (32u - d));
}

// Threefry-2x32, 20 rounds, matching jax._src.prng.threefry2x32.
__device__ __forceinline__ void threefry2x32(uint32_t k0, uint32_t k1,
                                             uint32_t x0, uint32_t x1,
                                             uint32_t& o0, uint32_t& o1) {
  uint32_t ks2 = k0 ^ k1 ^ 0x1BD11BDAu;
  x0 += k0; x1 += k1;
#define TF_ROUND(r) { x0 += x1; x1 = rotl32(x1, (r)); x1 ^= x0; }
  TF_ROUND(13) TF_ROUND(15) TF_ROUND(26) TF_ROUND(6)
  x0 += k1;  x1 += ks2 + 1u;
  TF_ROUND(17) TF_ROUND(29) TF_ROUND(16) TF_ROUND(24)
  x0 += ks2; x1 += k0 + 2u;
  TF_ROUND(13) TF_ROUND(15) TF_ROUND(26) TF_ROUND(6)
  x0 += k0;  x1 += k1 + 3u;
  TF_ROUND(17) TF_ROUND(29) TF_ROUND(16) TF_ROUND(24)
  x0 += k1;  x1 += ks2 + 4u;
  TF_ROUND(13) TF_ROUND(15) TF_ROUND(26) TF_ROUND(6)
  x0 += ks2; x1 += k0 + 5u;
#undef TF_ROUND
  o0 = x0; o1 = x1;
}

// partitionable random_bits, u32 = xor of the two threefry words (verified round 2)
__device__ __forceinline__ uint32_t jax_random_bits_u32(uint64_t n) {
  uint32_t o0, o1;
  threefry2x32(0u, 42u, (uint32_t)(n >> 32), (uint32_t)n, o0, o1);
  return o0 ^ o1;
}

// JAX: uniform(key, minval=tiny, maxval=1.) -> gumbel = -log(-log(u))
__device__ __forceinline__ float gumbel_from_bits(uint32_t bits) {
  const float tiny = 1.17549435e-38f;
  float f = __uint_as_float(0x3f800000u | (bits >> 9)) - 1.0f;  // [0,1)
  float u = f * 1.0f + tiny;
  u = fmaxf(tiny, u);
  return -logf(-logf(u));
}

// Monotone (ascending) uint mapping of float ordering.
__device__ __forceinline__ uint32_t sortkey(float x) {
  uint32_t b = __float_as_uint(x);
  uint32_t mask = (uint32_t)((int32_t)b >> 31) | 0x80000000u;
  return b ^ mask;
}

// Markstein exact division by block-invariant st: bit-identical to a/st
// (verified rounds 11-16: passed with absmax at bf16 rounding floor).
__device__ __forceinline__ float div_exact(float a, float st, float ry) {
  float q0 = a * ry;
  float r  = __builtin_fmaf(-st, q0, a);
  return __builtin_fmaf(r, ry, q0);
}

// ======================= k1: per-chunk scan (256-bin windowed cut) ==========
// grid = NBLK1 (3200) x 256. One 5120-elem chunk per block, register-resident.
// Raw sum-exp overflow-safe: |s| <= ~55 -> exp(s) <= 8e23, chunk sum <= 4e27.
// Common path: 256-bin float hist over [mxb-2.2*sigma, mxb], shfl prefix,
// extract bin<=cutbin (identical float expr as counting -> exact match).
// If extracted count not in [63, CSLOT]: exact full-hist fallback (r13 code).
__global__ __launch_bounds__(K1T) void k1_scan(
    const float* __restrict__ logits, const float* __restrict__ temps,
    float* __restrict__ out, uint32_t* __restrict__ cand_s,
    uint16_t* __restrict__ cand_i, float* __restrict__ m_arr,
    float* __restrict__ S_arr, uint32_t* __restrict__ cnt_arr) {

  __shared__ uint32_t histw[HBW];         // [0..255] = small hist; full = fallback
  __shared__ uint32_t ssum[K1T];          // fallback scan
  __shared__ float swm[4], sws[4];
  __shared__ uint32_t wtot[4];
  __shared__ int s_tstar;
  __shared__ uint32_t s_cutbin, s_cutkey, s_lcnt;

  const int bid = blockIdx.x;
  const int r = bid / JPB, j = bid - r * JPB;
  const int t = threadIdx.x;
  const int lane = t & 63, wv = t >> 6;
  const float temp = temps[r];
  const float st = (temp == 0.0f) ? 1.0f : temp;
  const float ry = 1.0f / st;

  const f4* __restrict__ lrow4 = (const f4*)(logits + (size_t)r * NV + (size_t)j * CH);
  f4* __restrict__ srow4 = (f4*)(out + NB + (size_t)r * NV + (size_t)j * CH);

  histw[t] = 0u;                          // zero the 256 small bins (K1T==256)
  if (t == 0) { s_lcnt = 0u; s_tstar = K1T - 1; s_cutbin = 255u; }

  // ---- pass A: Markstein-exact s=x/st + NT store, 4-chain sum/max ----
  f4 sreg[QPT];
  float mx0 = -INFINITY, mx1 = -INFINITY, mx2 = -INFINITY, mx3 = -INFINITY;
  float sm0 = 0.0f, sm1 = 0.0f, sm2 = 0.0f, sm3 = 0.0f;
  #pragma unroll
  for (int q = 0; q < QPT; ++q) {
    int i = q * K1T + t;
    f4 x = lrow4[i];
    f4 s;
    s.x = div_exact(x.x, st, ry);
    s.y = div_exact(x.y, st, ry);
    s.z = div_exact(x.z, st, ry);
    s.w = div_exact(x.w, st, ry);
    __builtin_nontemporal_store(s, srow4 + i);   // stream past L2
    sreg[q] = s;
    mx0 = fmaxf(mx0, s.x); mx1 = fmaxf(mx1, s.y);
    mx2 = fmaxf(mx2, s.z); mx3 = fmaxf(mx3, s.w);
    sm0 += __expf(s.x); sm1 += __expf(s.y);
    sm2 += __expf(s.z); sm3 += __expf(s.w);
  }
  float mx = fmaxf(fmaxf(mx0, mx1), fmaxf(mx2, mx3));
  float sum = (sm0 + sm1) + (sm2 + sm3);
  #pragma unroll
  for (int off = 32; off > 0; off >>= 1) {
    mx = fmaxf(mx, __shfl_xor(mx, off));
    sum += __shfl_xor(sum, off);
  }
  if (lane == 0) { swm[wv] = mx; sws[wv] = sum; }
  __syncthreads();                        // also publishes zeroed small hist
  const float mxb = fmaxf(fmaxf(swm[0], swm[1]), fmaxf(swm[2], swm[3]));
  if (t == 0) {
    m_arr[bid] = mxb;
    S_arr[bid] = sws[0] + sws[1] + sws[2] + sws[3];
  }
  // bins per s-unit: 256 bins over a WINSD*sigma_s window (sigma_s = ry)
  const float F = (256.0f / WINSD) * st;

  // ---- pass B: windowed 256-bin hist (bin 0 = chunk max) ----
  #pragma unroll
  for (int q = 0; q < QPT; ++q) {
    float sv[4] = {sreg[q].x, sreg[q].y, sreg[q].z, sreg[q].w};
    #pragma unroll
    for (int c = 0; c < 4; ++c) {
      float d = (mxb - sv[c]) * F;        // >= 0
      if (d < 256.0f) atomicAdd(&histw[(uint32_t)d], 1u);
    }
  }
  __syncthreads();

  // ---- prefix over 256 bins; winner bin where prefix first reaches 63 ----
  {
    uint32_t c = histw[t];
    uint32_t ps = c;
    #pragma unroll
    for (int off = 1; off < 64; off <<= 1) {
      uint32_t v = __shfl_up(ps, off);
      if (lane >= off) ps += v;
    }
    if (lane == 63) wtot[wv] = ps;
    __syncthreads();
    uint32_t add = 0;
    #pragma unroll
    for (int w2 = 0; w2 < 4; ++w2)
      if (w2 < wv) add += wtot[w2];
    ps += add;                             // inclusive prefix over bins 0..t
    if (ps >= 63u && (ps - c) < 63u) s_cutbin = (uint32_t)t;
  }
  __syncthreads();
  const uint32_t cutbin = s_cutbin;

  // ---- pass C: extract bin <= cutbin (IDENTICAL float expr as counting) ----
  uint32_t* __restrict__ mys = cand_s + (size_t)bid * CSLOT;
  uint16_t* __restrict__ myi = cand_i + (size_t)bid * CSLOT;
  #pragma unroll
  for (int q = 0; q < QPT; ++q) {
    float sv[4] = {sreg[q].x, sreg[q].y, sreg[q].z, sreg[q].w};
    #pragma unroll
    for (int c = 0; c < 4; ++c) {
      float d = (mxb - sv[c]) * F;
      if (d < 256.0f && (uint32_t)d <= cutbin) {
        uint32_t pos = atomicAdd(&s_lcnt, 1u);
        if (pos < CSLOT) {
          mys[pos] = __float_as_uint(sv[c]);
          myi[pos] = (uint16_t)((q * K1T + t) * 4 + c);
        }
      }
    }
  }
  __syncthreads();
  const uint32_t lc = s_lcnt;
  if (lc >= 63u && lc <= (uint32_t)CSLOT) {
    if (t == 0) cnt_arr[bid] = lc;
    return;                                // common path done
  }

  // ========== exact fallback: full 8192-bin hist (r13-proven code) ==========
  if (t == 0) s_lcnt = 0u;
  for (int i = t; i < HBW; i += K1T) histw[i] = 0u;
  __syncthreads();
  #pragma unroll
  for (int q = 0; q < QPT; ++q) {
    float sv[4] = {sreg[q].x, sreg[q].y, sreg[q].z, sreg[q].w};
    #pragma unroll
    for (int c = 0; c < 4; ++c) {
      uint32_t b = sortkey(sv[c]) >> 19;
      atomicAdd(&histw[b >> 1], (b & 1) ? 65536u : 1u);
    }
  }
  __syncthreads();
  uint32_t sloc = 0;
  #pragma unroll
  for (int u = 0; u < 16; ++u) {
    uint32_t w = histw[t * 16 + u];
    sloc += (w & 0xFFFFu) + (w >> 16);
  }
  ssum[t] = sloc;
  __syncthreads();
  for (int off = 1; off < K1T; off <<= 1) {
    uint32_t v = ssum[t] + ((t + off < K1T) ? ssum[t + off] : 0u);
    __syncthreads();
    ssum[t] = v;
    __syncthreads();
  }
  if (ssum[t] >= 63u && (t == K1T - 1 || ssum[t + 1] < 63u)) s_tstar = t;
  __syncthreads();
  if (t == 0) {
    int ts = s_tstar;
    uint32_t running = (ts == K1T - 1) ? 0u : ssum[ts + 1];
    int cb = ts * 32;
    for (int q = 31; q >= 0; --q) {
      uint32_t w = histw[ts * 16 + (q >> 1)];
      uint32_t c = (q & 1) ? (w >> 16) : (w & 0xFFFFu);
      running += c;
      if (running >= 63u) { cb = ts * 32 + q; break; }
    }
    s_cutkey = (uint32_t)cb << 19;
  }
  __syncthreads();
  const uint32_t cutkey = s_cutkey;
  #pragma unroll
  for (int q = 0; q < QPT; ++q) {
    float sv[4] = {sreg[q].x, sreg[q].y, sreg[q].z, sreg[q].w};
    #pragma unroll
    for (int c = 0; c < 4; ++c) {
      if (sortkey(sv[c]) >= cutkey) {
        uint32_t pos = atomicAdd(&s_lcnt, 1u);
        if (pos < CSLOT) {
          mys[pos] = __float_as_uint(sv[c]);
          myi[pos] = (uint16_t)((q * K1T + t) * 4 + c);
        }
      }
    }
  }
  __syncthreads();
  if (t == 0) cnt_arr[bid] = (s_lcnt < CSLOT) ? s_lcnt : (uint32_t)CSLOT;
}

// ======================= k2: per-row finalize (search-free gather) ==========
__global__ __launch_bounds__(K1T) void k2_final(
    const float* __restrict__ temps, const float* __restrict__ topps,
    const float* __restrict__ topks, const uint32_t* __restrict__ cand_s,
    const uint16_t* __restrict__ cand_i, const float* __restrict__ m_arr,
    const float* __restrict__ S_arr, const uint32_t* __restrict__ cnt_arr,
    float* __restrict__ out) {

  __shared__ unsigned long long sc[SCCAP];   // 20.8 KB (holey staging)
  __shared__ uint32_t nhist[NHB];            // 8 KB
  __shared__ unsigned long long sn[SNCAP];   // 2 KB
  __shared__ float sm8[32], ss8[32];
  __shared__ uint32_t scnt8[JPB];
  __shared__ uint32_t swsum[4];
  __shared__ uint32_t s_cutp, s_scnt;
  __shared__ float s_m, s_Z;
  __shared__ float sp[TOPC], scum[TOPC], slv[TOPC];
  __shared__ int sidx_[TOPC];

  const int r = blockIdx.x;
  const int t = threadIdx.x;
  const int lane = t & 63, wv = t >> 6;
  const float temp = temps[r];

  if (t < 32) {
    sm8[t] = (t < JPB) ? m_arr[r * JPB + t] : -INFINITY;
    ss8[t] = (t < JPB) ? S_arr[r * JPB + t] : 0.0f;
  }
  if (t < JPB) scnt8[t] = cnt_arr[r * JPB + t];
  for (int i = t; i < NHB; i += K1T) nhist[i] = 0u;
  __syncthreads();
  if (t == 0) {
    float m = -INFINITY;
    for (int q = 0; q < JPB; ++q) m = fmaxf(m, sm8[q]);
    float Sr = 0.0f;
    for (int q = 0; q < JPB; ++q) Sr += ss8[q];
    s_m = m;
    s_Z = Sr * expf(-m);   // uniform per-row scalar (order-safe)
    s_scnt = 0u;
  }
  __syncthreads();
  const float m = s_m, Z = s_Z;

  // gather: direct (chunk, slot) indexing -- no linear search, holes skipped
  for (int e = t; e < SCCAP; e += K1T) {
    int q = e / CSLOT;
    int slot = e - q * CSLOT;
    if (slot < (int)scnt8[q]) {
      int gs = (r * JPB + q) * CSLOT + slot;
      float s = __uint_as_float(cand_s[gs]);
      uint32_t idx = (uint32_t)q * CH + (uint32_t)cand_i[gs];
      float p = expf(s - m) / Z;
      sc[e] = ((unsigned long long)__float_as_uint(p) << 32)
            | (unsigned long long)(0xFFFFFFFFu - idx);
      atomicAdd(&nhist[__float_as_uint(p) >> 21], 1u);
    }
  }
  __syncthreads();

  // narrow cut on p-bits: thread t owns bins [t*8, t*8+8)
  uint32_t nloc = 0;
  #pragma unroll
  for (int u = 0; u < 8; ++u) nloc += nhist[t * 8 + u];
  uint32_t ns = nloc;
  #pragma unroll
  for (int off = 1; off < 64; off <<= 1) {
    uint32_t v = __shfl_down(ns, off);
    if (lane + off < 64) ns += v;
  }
  if (lane == 0) swsum[wv] = ns;
  __syncthreads();
  #pragma unroll
  for (int w2 = 0; w2 < 4; ++w2)
    if (w2 > wv) ns += swsum[w2];
  if (ns >= 63u && (ns - nloc) < 63u) {
    uint32_t running = ns - nloc;
    int cutbin = t * 8;
    for (int u = 7; u >= 0; --u) {
      running += nhist[t * 8 + u];
      if (running >= 63u) { cutbin = t * 8 + u; break; }
    }
    s_cutp = (uint32_t)cutbin << 21;
  }
  __syncthreads();
  const uint32_t cutp = s_cutp;

  for (int e = t; e < SCCAP; e += K1T) {
    int q = e / CSLOT;
    int slot = e - q * CSLOT;
    if (slot < (int)scnt8[q]) {
      unsigned long long v = sc[e];
      if ((uint32_t)(v >> 32) >= cutp) {
        uint32_t pos = atomicAdd(&s_scnt, 1u);
        if (pos < SNCAP) sn[pos] = v;
      }
    }
  }
  __syncthreads();
  const uint32_t scnt = s_scnt;
  if (t < SNCAP && t >= (int)scnt) sn[t] = 0ull;
  __syncthreads();

  // bitonic sort SNCAP keys descending => (p desc, idx asc)
  for (int k = 2; k <= SNCAP; k <<= 1) {
    for (int jj = k >> 1; jj > 0; jj >>= 1) {
      int e = t;
      int ixj = e ^ jj;
      if (ixj > e) {
        unsigned long long a = sn[e], c = sn[ixj];
        bool desc = ((e & k) == 0);
        if (desc ? (a < c) : (a > c)) { sn[e] = c; sn[ixj] = a; }
      }
      __syncthreads();
    }
  }

  // ---- top-63 tail (validated rounds 2-16) ----
  if (t < TOPC) {
    unsigned long long kv = sn[t];
    sp[t] = __uint_as_float((uint32_t)(kv >> 32));
    sidx_[t] = (int)(0xFFFFFFFFu - (uint32_t)(kv & 0xFFFFFFFFull));
  }
  __syncthreads();
  if (t == 0) {
    float L0[63], L1[31], L2[15], L3[7], L4[3];
    for (int i = 0; i < 63; ++i) L0[i] = sp[i];
    for (int i = 0; i < 31; ++i) L1[i] = L0[2*i] + L0[2*i+1];
    for (int i = 0; i < 15; ++i) L2[i] = L1[2*i] + L1[2*i+1];
    for (int i = 0; i < 7;  ++i) L3[i] = L2[2*i] + L2[2*i+1];
    for (int i = 0; i < 3;  ++i) L4[i] = L3[2*i] + L3[2*i+1];
    float S5 = L4[0] + L4[1];
    float S4[3]; S4[0] = L4[0]; S4[1] = S5; S4[2] = S5 + L4[2];
    float S3[7]; S3[0] = L3[0];
    for (int k = 0; k < 3; ++k) { S3[2*k+1] = S4[k]; if (2*k+2 < 7)  S3[2*k+2] = S4[k] + L3[2*k+2]; }
    float S2[15]; S2[0] = L2[0];
    for (int k = 0; k < 7; ++k) { S2[2*k+1] = S3[k]; if (2*k+2 < 15) S2[2*k+2] = S3[k] + L2[2*k+2]; }
    float S1[31]; S1[0] = L1[0];
    for (int k = 0; k < 15; ++k){ S1[2*k+1] = S2[k]; if (2*k+2 < 31) S1[2*k+2] = S2[k] + L1[2*k+2]; }
    scum[0] = L0[0];
    for (int k = 0; k < 31; ++k){ scum[2*k+1] = S1[k]; if (2*k+2 < 63) scum[2*k+2] = S1[k] + L0[2*k+2]; }
  }
  __syncthreads();
  if (t < TOPC) {
    const float topp = topps[r];
    const float topk = topks[r];
    bool keep = (((float)t < topk) && ((scum[t] - sp[t]) < topp)) || (t == 0);
    uint32_t bits = jax_random_bits_u32((uint64_t)r * NV + (uint64_t)t);
    float g = gumbel_from_bits(bits);
    slv[t] = keep ? (logf(sp[t]) + g) : -INFINITY;
  }
  __syncthreads();
  if (t == 0) {
    float best = slv[0]; int br = 0;
    for (int q = 1; q < TOPC; ++q)
      if (slv[q] > best) { best = slv[q]; br = q; }
    int id = (temp == 0.0f) ? sidx_[0] : sidx_[br];
    out[r] = (float)id;
  }
}

// ======================= fallback: round-2 monolithic kernel =======================

__global__ __launch_bounds__(NT) void sampler_kernel(
    const float* __restrict__ logits, const float* __restrict__ temps,
    const float* __restrict__ topps, const float* __restrict__ topks,
    float* __restrict__ out) {

  __shared__ union {
    uint32_t hist[NBINS];
    unsigned long long cand[CCAP];
  } sh;
  __shared__ uint32_t ssum[NT];
  __shared__ float redf[NT];
  __shared__ uint32_t s_cutkey, s_cnt;
  __shared__ int s_tstar;
  __shared__ float sp[TOPC], scum[TOPC], slv[TOPC];
  __shared__ int sidx_[TOPC];

  const int b = blockIdx.x;
  const int t = threadIdx.x;
  const float temp = temps[b];
  const float st = (temp == 0.0f) ? 1.0f : temp;
  const float topp = topps[b];
  const float topk = topks[b];

  const float4* __restrict__ lrow = (const float4*)(logits + (size_t)b * NV);
  float4* __restrict__ srow = (float4*)(out + NB + (size_t)b * NV);

  for (int i = t; i < NBINS; i += NT) sh.hist[i] = 0u;
  if (t == 0) s_tstar = NT - 1;

  float lmax = -INFINITY;
  for (int i = t; i < NV4; i += NT) {
    float4 x = lrow[i];
    float4 s;
    s.x = x.x / st; s.y = x.y / st; s.z = x.z / st; s.w = x.w / st;
    srow[i] = s;
    lmax = fmaxf(lmax, fmaxf(fmaxf(s.x, s.y), fmaxf(s.z, s.w)));
  }
  redf[t] = lmax;
  __syncthreads();
  for (int off = NT / 2; off > 0; off >>= 1) {
    if (t < off) redf[t] = fmaxf(redf[t], redf[t + off]);
    __syncthreads();
  }
  const float m = redf[0];
  __syncthreads();

  float lsum = 0.0f;
  for (int i = t; i < NV4; i += NT) {
    float4 x = lrow[i];
    float s0 = x.x / st, s1 = x.y / st, s2 = x.z / st, s3 = x.w / st;
    lsum += expf(s0 - m); lsum += expf(s1 - m);
    lsum += expf(s2 - m); lsum += expf(s3 - m);
    atomicAdd(&sh.hist[sortkey(s0) >> 18], 1u);
    atomicAdd(&sh.hist[sortkey(s1) >> 18], 1u);
    atomicAdd(&sh.hist[sortkey(s2) >> 18], 1u);
    atomicAdd(&sh.hist[sortkey(s3) >> 18], 1u);
  }
  redf[t] = lsum;
  __syncthreads();
  for (int off = NT / 2; off > 0; off >>= 1) {
    if (t < off) redf[t] += redf[t + off];
    __syncthreads();
  }
  const float Z = redf[0];
  __syncthreads();

  uint32_t sloc = 0;
  #pragma unroll
  for (int j = 0; j < 16; ++j) sloc += sh.hist[t * 16 + j];
  ssum[t] = sloc;
  __syncthreads();
  for (int off = 1; off < NT; off <<= 1) {
    uint32_t v = ssum[t] + ((t + off < NT) ? ssum[t + off] : 0u);
    __syncthreads();
    ssum[t] = v;
    __syncthreads();
  }
  if (ssum[t] >= 63u && (t == NT - 1 || ssum[t + 1] < 63u)) s_tstar = t;
  __syncthreads();
  if (t == 0) {
    int ts = s_tstar;
    uint32_t running = (ts == NT - 1) ? 0u : ssum[ts + 1];
    int cutbin = ts * 16;
    for (int j = 15; j >= 0; --j) {
      running += sh.hist[ts * 16 + j];
      if (running >= 63u) { cutbin = ts * 16 + j; break; }
    }
    s_cutkey = (uint32_t)cutbin << 18;
    s_cnt = 0u;
  }
  __syncthreads();
  const uint32_t cutkey = s_cutkey;

  for (int i = t; i < NV4; i += NT) {
    float4 x = lrow[i];
    float sv[4];
    sv[0] = x.x / st; sv[1] = x.y / st; sv[2] = x.z / st; sv[3] = x.w / st;
    #pragma unroll
    for (int j = 0; j < 4; ++j) {
      uint32_t key = sortkey(sv[j]);
      if (key >= cutkey) {
        float p = expf(sv[j] - m) / Z;
        uint32_t pos = atomicAdd(&s_cnt, 1u);
        if (pos < CCAP) {
          uint32_t idx = (uint32_t)(i * 4 + j);
          sh.cand[pos] = ((unsigned long long)__float_as_uint(p) << 32)
                       | (unsigned long long)(0xFFFFFFFFu - idx);
        }
      }
    }
  }
  __syncthreads();
  const uint32_t cnt = s_cnt;
  for (int e = t; e < CCAP; e += NT)
    if ((uint32_t)e >= cnt) sh.cand[e] = 0ull;
  __syncthreads();

  for (uint32_t k = 2; k <= CCAP; k <<= 1) {
    for (uint32_t j = k >> 1; j > 0; j >>= 1) {
      for (int e = t; e < CCAP; e += NT) {
        uint32_t ixj = (uint32_t)e ^ j;
        if (ixj > (uint32_t)e) {
          unsigned long long a = sh.cand[e], c = sh.cand[ixj];
          bool desc = (((uint32_t)e & k) == 0u);
          if (desc ? (a < c) : (a > c)) { sh.cand[e] = c; sh.cand[ixj] = a; }
        }
      }
      __syncthreads();
    }
  }

  if (t < TOPC) {
    unsigned long long kv = sh.cand[t];
    sp[t] = __uint_as_float((uint32_t)(kv >> 32));
    sidx_[t] = (int)(0xFFFFFFFFu - (uint32_t)(kv & 0xFFFFFFFFull));
  }
  __syncthreads();
  if (t == 0) {
    float L0[63], L1[31], L2[15], L3[7], L4[3];
    for (int i = 0; i < 63; ++i) L0[i] = sp[i];
    for (int i = 0; i < 31; ++i) L1[i] = L0[2*i] + L0[2*i+1];
    for (int i = 0; i < 15; ++i) L2[i] = L1[2*i] + L1[2*i+1];
    for (int i = 0; i < 7;  ++i) L3[i] = L2[2*i] + L2[2*i+1];
    for (int i = 0; i < 3;  ++i) L4[i] = L3[2*i] + L3[2*i+1];
    float S5 = L4[0] + L4[1];
    float S4[3]; S4[0] = L4[0]; S4[1] = S5; S4[2] = S5 + L4[2];
    float S3[7]; S3[0] = L3[0];
    for (int k = 0; k < 3; ++k) { S3[2*k+1] = S4[k]; if (2*k+2 < 7)  S3[2*k+2] = S4[k] + L3[2*k+2]; }
    float S2[15]; S2[0] = L2[0];
    for (int k = 0; k < 7; ++k) { S2[2*k+1] = S3[k]; if (2*k+2 < 15) S2[2*k+2] = S3[k] + L2[2*k+2]; }
    float S1[31]; S1[0] = L1[0];
    for (int k = 0; k < 15; ++k){ S1[2*k+1] = S2[k]; if (2*k+2 < 31) S1[2*k+2] = S2[k] + L1[2*k+2]; }
    scum[0] = L0[0];
    for (int k = 0; k < 31; ++k){ scum[2*k+1] = S1[k]; if (2*k+2 < 63) scum[2*k+2] = S1[k] + L0[2*k+2]; }
  }
  __syncthreads();
  if (t < TOPC) {
    bool keep = (((float)t < topk) && ((scum[t] - sp[t]) < topp)) || (t == 0);
    uint32_t bits = jax_random_bits_u32((uint64_t)b * NV + (uint64_t)t);
    float g = gumbel_from_bits(bits);
    slv[t] = keep ? (logf(sp[t]) + g) : -INFINITY;
  }
  __syncthreads();
  if (t == 0) {
    float best = slv[0]; int br = 0;
    for (int q = 1; q < TOPC; ++q)
      if (slv[q] > best) { best = slv[q]; br = q; }
    int id = (temp == 0.0f) ? sidx_[0] : sidx_[br];
    out[b] = (float)id;
  }
}

extern "C" void kernel_launch(void* const* d_in, const int* in_sizes, int n_in,
                              void* d_out, int out_size, void* d_ws, size_t ws_size,
                              hipStream_t stream) {
  const float* logits = (const float*)d_in[0];
  const float* temps  = (const float*)d_in[1];
  const float* topps  = (const float*)d_in[2];
  const float* topks  = (const float*)d_in[3];
  float* out = (float*)d_out;

  if (ws_size >= WS_NEED) {
    uint32_t* cand_s  = (uint32_t*)((char*)d_ws + WS_CS_OFF);
    uint16_t* cand_i  = (uint16_t*)((char*)d_ws + WS_CI_OFF);
    float*    m_arr   = (float*)((char*)d_ws + WS_M_OFF);
    float*    S_arr   = (float*)((char*)d_ws + WS_S_OFF);
    uint32_t* cnt_arr = (uint32_t*)((char*)d_ws + WS_CNT_OFF);
    hipLaunchKernelGGL(k1_scan, dim3(NBLK1), dim3(K1T), 0, stream,
                       logits, temps, out, cand_s, cand_i, m_arr, S_arr, cnt_arr);
    hipLaunchKernelGGL(k2_final, dim3(NB), dim3(K1T), 0, stream,
                       temps, topps, topks, cand_s, cand_i,
                       m_arr, S_arr, cnt_arr, out);
  } else {
    hipLaunchKernelGGL(sampler_kernel, dim3(NB), dim3(NT), 0, stream,
                       logits, temps, topps, topks, out);
  }
}